// Round 6
// baseline (20.892 us; speedup 1.0000x reference)
//
#include <hip/hip_runtime.h>

#define TT 512
#define BB 32
#define CC 8000
#define LOG2E 1.4426950408889634f
#define LN2   0.6931471805599453f

#if __has_builtin(__builtin_amdgcn_exp2f)
#define EXP2F(x) __builtin_amdgcn_exp2f(x)
#else
#define EXP2F(x) exp2f(x)
#endif
#if __has_builtin(__builtin_amdgcn_logf)
#define LOG2F(x) __builtin_amdgcn_logf(x)   // v_log_f32 = log2
#else
#define LOG2F(x) log2f(x)
#endif

// ws layout (floats): chunk c, batch b occupies 16 contiguous floats at
//   ws + c*512 + b*16 :  [M00,M01,M02,M03, M04,M11,M12,M13,
//                         M14,M22,M23,M24, M33,M34,M44,Ec]
// (4 float4s per lane -> phase B loads are 4x dwordx4).
// Election counter (uint) at float index 65*512; needs NO init: 32 consecutive
// atomicAdd results cover every residue mod 32 exactly once, so exactly one
// block sees (old & 31)==31 for any starting value.
#define WS_CNT_OFF (65 * 512 * 4)

// ---- Phase B helpers (X = bank array float4[4][4], g = compile-time group) --
#define LOAD_GROUP(X, g)                                                       \
    _Pragma("unroll")                                                          \
    for (int j = 0; j < 4; ++j) {                                              \
        const float4* src =                                                    \
            (const float4*)(ws + (size_t)(4 * (g) + j) * 512 + bb * 16);       \
        X[j][0] = src[0]; X[j][1] = src[1]; X[j][2] = src[2]; X[j][3] = src[3];\
    }

#define COMPUTE_GROUP(X)                                                       \
    _Pragma("unroll")                                                          \
    for (int j = 0; j < 4; ++j) {                                              \
        float4 v0 = X[j][0], v1 = X[j][1], v2 = X[j][2], v3 = X[j][3];         \
        float B0 = A0 * v0.x;                                                  \
        float B1 = fmaf(A0, v0.y, A1 * v1.y);                                  \
        float B2 = fmaf(A0, v0.z, fmaf(A1, v1.z, A2 * v2.y));                  \
        float B3 = fmaf(A0, v0.w, fmaf(A1, v1.w, fmaf(A2, v2.z, A3 * v3.x)));  \
        float B4 = fmaf(A0, v1.x, fmaf(A1, v2.x, fmaf(A2, v2.w,                \
                        fmaf(A3, v3.y, A4 * v3.z))));                          \
        Ed += (double)v3.w;                                                    \
        float mx = fmaxf(fmaxf(fmaxf(B0, B1), fmaxf(B2, B3)), B4);             \
        int ex = (int)((__float_as_uint(mx) >> 23) & 0xffu) - 127;             \
        float sc = __uint_as_float((unsigned)(127 - ex) << 23); /* 2^-ex */    \
        Ei += ex;                                                              \
        A0 = B0 * sc; A1 = B1 * sc; A2 = B2 * sc; A3 = B3 * sc; A4 = B4 * sc;  \
    }

// 32 blocks x 64 threads. Phase A: thread (c,b) builds chunk c's 5x5 linear
// (probability-domain) transition product with per-step pow2 normalization.
// Last-arriving block runs the 64-chunk serial scan (phase B) in one wave,
// with a 3-bank distance-2 register pipeline hiding the ws load latency.
__global__ __launch_bounds__(64) void ctc_fused(
        const float* __restrict__ logit,
        const int* __restrict__ targets,
        float* __restrict__ ws,
        unsigned int* __restrict__ cnt,
        float* __restrict__ out) {
    int tid = threadIdx.x;
    int gid = blockIdx.x * 64 + tid;           // 0..2047
    int b = gid & 31;
    int c = gid >> 5;                          // 0..63
    int a1 = targets[2 * b];
    int a2 = targets[2 * b + 1];
    float skf = (a1 != a2) ? 1.0f : 0.0f;      // skip transition 1->3 allowed?

    // ---------------- Phase A ----------------
    int tstart = (c == 0) ? 1 : 8 * c;
    int nst    = (c == 0) ? 7 : 8;

    float l0[8], la[8], lb[8];
    #pragma unroll
    for (int s = 0; s < 8; ++s) {              // s=7 of chunk 0 reads t=8: in-bounds, unused
        const float* row = logit + (size_t)((tstart + s) * BB + b) * CC;
        l0[s] = row[0]  * LOG2E;
        la[s] = row[a1] * LOG2E;
        lb[s] = row[a2] * LOG2E;
    }

    // Init M = T_{tstart} (normalized). pred: 0<-{0}; 1<-{0,1}; 2<-{1,2};
    // 3<-{1(sk),2,3}; 4<-{3,4}. Emissions: 0,2,4 blank; 1 -> a1; 3 -> a2.
    float m0s = fmaxf(fmaxf(l0[0], la[0]), lb[0]);
    float P0 = EXP2F(l0[0] - m0s), Pa = EXP2F(la[0] - m0s), Pb = EXP2F(lb[0] - m0s);
    float Ec = m0s;
    float M00 = P0, M01 = Pa, M02 = 0.f, M03 = 0.f, M04 = 0.f;
    float M11 = Pa, M12 = P0, M13 = skf * Pb, M14 = 0.f;
    float M22 = P0, M23 = Pb, M24 = 0.f;
    float M33 = Pb, M34 = P0;
    float M44 = P0;

    #pragma unroll
    for (int s = 1; s < 8; ++s) {
        if (s >= nst) break;                   // only chunk 0 stops at 7
        float ms = fmaxf(fmaxf(l0[s], la[s]), lb[s]);
        float q0 = EXP2F(l0[s] - ms);
        float qa = EXP2F(la[s] - ms);
        float qb = EXP2F(lb[s] - ms);
        Ec += ms;
        float n00 = M00 * q0;
        float n01 = (M00 + M01) * qa;
        float n02 = (M01 + M02) * q0;
        float n03 = fmaf(skf, M01, M02 + M03) * qb;
        float n04 = (M03 + M04) * q0;
        float n11 = M11 * qa;
        float n12 = (M11 + M12) * q0;
        float n13 = fmaf(skf, M11, M12 + M13) * qb;
        float n14 = (M13 + M14) * q0;
        float n22 = M22 * q0;
        float n23 = (M22 + M23) * qb;
        float n24 = (M23 + M24) * q0;
        float n33 = M33 * qb;
        float n34 = (M33 + M34) * q0;
        float n44 = M44 * q0;
        M00 = n00; M01 = n01; M02 = n02; M03 = n03; M04 = n04;
        M11 = n11; M12 = n12; M13 = n13; M14 = n14;
        M22 = n22; M23 = n23; M24 = n24;
        M33 = n33; M34 = n34;
        M44 = n44;
    }

    {
        float4* w = (float4*)(ws + (size_t)c * 512 + b * 16);
        w[0] = make_float4(M00, M01, M02, M03);
        w[1] = make_float4(M04, M11, M12, M13);
        w[2] = make_float4(M14, M22, M23, M24);
        w[3] = make_float4(M33, M34, M44, Ec);
    }

    // ---------------- Publish + elect last block (no counter init needed) ----
    __threadfence();                 // release: ws writes to coherence point
    __syncthreads();
    __shared__ unsigned int sh_old;
    if (tid == 0) sh_old = atomicAdd(cnt, 1u);
    __syncthreads();
    if ((sh_old & 31u) != 31u) return;
    __threadfence();                 // acquire: drop stale cached ws lines

    // ---------------- Phase B (last block; one wave) ----------------
    int bb = (tid < BB) ? tid : 0;
    int t1 = targets[2 * bb];
    const float* row0 = logit + (size_t)bb * CC;
    float l00 = row0[0] * LOG2E, la0 = row0[t1] * LOG2E;
    float mi = fmaxf(l00, la0);
    float A0 = EXP2F(l00 - mi), A1 = EXP2F(la0 - mi);
    float A2 = 0.f, A3 = 0.f, A4 = 0.f;
    double Ed = (double)mi;          // exponent: double + exact int, no drift
    int    Ei = 0;

    // 3 register banks x 4 chunks x 4 float4; fully unrolled so every index is
    // compile-time (keeps banks in VGPRs, ~200 VGPR total; 1 wave, no occupancy
    // concern). Distance-2 prefetch: ~480 cy of compute covers ~450 cy latency.
    float4 Abk[4][4], Bbk[4][4], Cbk[4][4];
    LOAD_GROUP(Abk, 0)
    LOAD_GROUP(Bbk, 1)
    LOAD_GROUP(Cbk, 2)
    #pragma unroll
    for (int g = 0; g < 16; ++g) {
        if (g % 3 == 0) {
            COMPUTE_GROUP(Abk)
            if (g + 3 < 16) { LOAD_GROUP(Abk, g + 3) }
        } else if (g % 3 == 1) {
            COMPUTE_GROUP(Bbk)
            if (g + 3 < 16) { LOAD_GROUP(Bbk, g + 3) }
        } else {
            COMPUTE_GROUP(Cbk)
            if (g + 3 < 16) { LOAD_GROUP(Cbk, g + 3) }
        }
    }

    float ll2 = (float)(Ed + (double)Ei) + LOG2F(A3 + A4);   // log2 likelihood
    float loss = (tid < BB) ? (-0.5f * LN2 * ll2) : 0.0f;    // -loglik_e / L
    #pragma unroll
    for (int off = 32; off > 0; off >>= 1)
        loss += __shfl_down(loss, off, 64);
    if (tid == 0) out[0] = loss * (1.0f / BB);
}

extern "C" void kernel_launch(void* const* d_in, const int* in_sizes, int n_in,
                              void* d_out, int out_size, void* d_ws, size_t ws_size,
                              hipStream_t stream) {
    const float* logit   = (const float*)d_in[0];
    const int*   targets = (const int*)d_in[2];
    float*        ws  = (float*)d_ws;
    unsigned int* cnt = (unsigned int*)((char*)d_ws + WS_CNT_OFF);
    float*        out = (float*)d_out;

    hipLaunchKernelGGL(ctc_fused, dim3(32), dim3(64), 0, stream,
                       logit, targets, ws, cnt, out);
}

// Round 7
// 11.898 us; speedup vs baseline: 1.7559x; 1.7559x over previous
//
#include <hip/hip_runtime.h>

#define TT 512
#define BB 32
#define CC 8000
#define LOG2E 1.4426950408889634f
#define LN2   0.6931471805599453f
#define NBLK  8

#if __has_builtin(__builtin_amdgcn_exp2f)
#define EXP2F(x) __builtin_amdgcn_exp2f(x)
#else
#define EXP2F(x) exp2f(x)
#endif
#if __has_builtin(__builtin_amdgcn_logf)
#define LOG2F(x) __builtin_amdgcn_logf(x)   // v_log_f32 = log2
#else
#define LOG2F(x) log2f(x)
#endif

// ws: block bk's combined matrix for batch b = 16 floats at ws + bk*512 + b*16:
//   [M00,M01,M02,M03][M04,M11,M12,M13][M14,M22,M23,M24][M33,M34,M44,E]
// Election counter at byte offset 65*512*4 (same slot as prior rounds; no init
// needed: 8 consecutive atomicAdd results cover all residues mod 8 once).
#define WS_CNT_OFF (65 * 512 * 4)

// Packed upper-tri index map: 0:00 1:01 2:02 3:03 4:04 5:11 6:12 7:13 8:14
//                             9:22 10:23 11:24 12:33 13:34 14:44
__device__ __forceinline__ void triprod(const float a[15], const float b[15],
                                        float p[15]) {
    p[ 0] = a[0] * b[0];
    p[ 1] = fmaf(a[0], b[ 1], a[1] * b[ 5]);
    p[ 2] = fmaf(a[0], b[ 2], fmaf(a[1], b[ 6], a[2] * b[ 9]));
    p[ 3] = fmaf(a[0], b[ 3], fmaf(a[1], b[ 7], fmaf(a[2], b[10], a[3] * b[12])));
    p[ 4] = fmaf(a[0], b[ 4], fmaf(a[1], b[ 8], fmaf(a[2], b[11],
                 fmaf(a[3], b[13], a[4] * b[14]))));
    p[ 5] = a[5] * b[5];
    p[ 6] = fmaf(a[5], b[ 6], a[6] * b[ 9]);
    p[ 7] = fmaf(a[5], b[ 7], fmaf(a[6], b[10], a[7] * b[12]));
    p[ 8] = fmaf(a[5], b[ 8], fmaf(a[6], b[11], fmaf(a[7], b[13], a[8] * b[14])));
    p[ 9] = a[9] * b[9];
    p[10] = fmaf(a[9], b[10], a[10] * b[12]);
    p[11] = fmaf(a[9], b[11], fmaf(a[10], b[13], a[11] * b[14]));
    p[12] = a[12] * b[12];
    p[13] = fmaf(a[12], b[13], a[13] * b[14]);
    p[14] = a[14] * b[14];
}

// Exact power-of-2 renorm; returns the exponent removed (as float, exact).
__device__ __forceinline__ float renorm15(float p[15]) {
    float mx = p[0];
    #pragma unroll
    for (int i = 1; i < 15; ++i) mx = fmaxf(mx, p[i]);
    int ex = (int)((__float_as_uint(mx) >> 23) & 0xffu) - 127;
    float sc = __uint_as_float((unsigned)(127 - ex) << 23);   // 2^-ex
    #pragma unroll
    for (int i = 0; i < 15; ++i) p[i] *= sc;
    return (float)ex;
}

// 8 blocks x 256 threads. Thread (c,b) builds chunk c's 5x5 linear transition
// product (pow2-normalized). Wave pair-combine (shfl) -> 2 chunks/wave; wave 0
// tree-combines the block's 4 via LDS -> 1 matrix/block; 8 matrices cross the
// device fence; last block chains 8 mat-vecs.
__global__ __launch_bounds__(256) void ctc_fused(
        const float* __restrict__ logit,
        const int* __restrict__ targets,
        float* __restrict__ ws,
        unsigned int* __restrict__ cnt,
        float* __restrict__ out) {
    __shared__ float lds[4 * 512];

    int tid = threadIdx.x;
    int bk  = blockIdx.x;
    int b   = tid & 31;
    int widx = tid >> 6;                        // wave 0..3
    int c   = bk * 8 + (tid >> 5);              // chunk 0..63
    int a1 = targets[2 * b];
    int a2 = targets[2 * b + 1];
    float skf = (a1 != a2) ? 1.0f : 0.0f;

    // ---------------- Phase A: per-chunk product ----------------
    int tstart = (c == 0) ? 1 : 8 * c;
    int nst    = (c == 0) ? 7 : 8;

    float l0[8], la[8], lb[8];
    #pragma unroll
    for (int s = 0; s < 8; ++s) {               // chunk 0's s=7 reads t=8: unused
        const float* row = logit + (size_t)((tstart + s) * BB + b) * CC;
        l0[s] = row[0]  * LOG2E;
        la[s] = row[a1] * LOG2E;
        lb[s] = row[a2] * LOG2E;
    }

    float m0s = fmaxf(fmaxf(l0[0], la[0]), lb[0]);
    float P0 = EXP2F(l0[0] - m0s), Pa = EXP2F(la[0] - m0s), Pb = EXP2F(lb[0] - m0s);
    float Ec = m0s;
    float M00 = P0, M01 = Pa, M02 = 0.f, M03 = 0.f, M04 = 0.f;
    float M11 = Pa, M12 = P0, M13 = skf * Pb, M14 = 0.f;
    float M22 = P0, M23 = Pb, M24 = 0.f;
    float M33 = Pb, M34 = P0;
    float M44 = P0;

    #pragma unroll
    for (int s = 1; s < 8; ++s) {
        if (s >= nst) break;
        float ms = fmaxf(fmaxf(l0[s], la[s]), lb[s]);
        float q0 = EXP2F(l0[s] - ms);
        float qa = EXP2F(la[s] - ms);
        float qb = EXP2F(lb[s] - ms);
        Ec += ms;
        float n00 = M00 * q0;
        float n01 = (M00 + M01) * qa;
        float n02 = (M01 + M02) * q0;
        float n03 = fmaf(skf, M01, M02 + M03) * qb;
        float n04 = (M03 + M04) * q0;
        float n11 = M11 * qa;
        float n12 = (M11 + M12) * q0;
        float n13 = fmaf(skf, M11, M12 + M13) * qb;
        float n14 = (M13 + M14) * q0;
        float n22 = M22 * q0;
        float n23 = (M22 + M23) * qb;
        float n24 = (M23 + M24) * q0;
        float n33 = M33 * qb;
        float n34 = (M33 + M34) * q0;
        float n44 = M44 * q0;
        M00 = n00; M01 = n01; M02 = n02; M03 = n03; M04 = n04;
        M11 = n11; M12 = n12; M13 = n13; M14 = n14;
        M22 = n22; M23 = n23; M24 = n24;
        M33 = n33; M34 = n34;
        M44 = n44;
    }

    float lo[15] = {M00,M01,M02,M03,M04,M11,M12,M13,M14,M22,M23,M24,M33,M34,M44};

    // ---- Wave pair-combine: lane<32 computes M_even * M_odd via shfl ----
    float hi[15];
    #pragma unroll
    for (int i = 0; i < 15; ++i) hi[i] = __shfl_down(lo[i], 32, 64);
    float Ehi = __shfl_down(Ec, 32, 64);
    float pw[15];
    triprod(lo, hi, pw);
    float Ew = Ec + Ehi + renorm15(pw);

    if ((tid & 63) < 32) {
        float* d = lds + widx * 512 + b * 16;
        #pragma unroll
        for (int i = 0; i < 15; ++i) d[i] = pw[i];
        d[15] = Ew;
    }
    __syncthreads();
    if (tid >= 64) return;

    // ---- Wave 0: tree-combine W0*W1*W2*W3 (W0 = own pw in regs) ----
    float w1[16], w2[16], w3[16];
    {
        const float* s1 = lds + 1 * 512 + b * 16;
        const float* s2 = lds + 2 * 512 + b * 16;
        const float* s3 = lds + 3 * 512 + b * 16;
        #pragma unroll
        for (int i = 0; i < 16; ++i) { w1[i] = s1[i]; w2[i] = s2[i]; w3[i] = s3[i]; }
    }
    float q1[15], q2[15], pf[15];
    triprod(pw, w1, q1);
    float E1 = Ew + w1[15] + renorm15(q1);
    triprod(w2, w3, q2);
    float E2 = w2[15] + w3[15] + renorm15(q2);
    triprod(q1, q2, pf);
    float Ef = E1 + E2 + renorm15(pf);

    // alpha0 loads issued early (cold HBM) to overlap with fence/election
    int t1 = targets[2 * b];
    const float* row0 = logit + (size_t)b * CC;
    float l00 = row0[0] * LOG2E, la0 = row0[t1] * LOG2E;

    if (tid < 32) {
        float4* w = (float4*)(ws + (size_t)bk * 512 + b * 16);
        w[0] = make_float4(pf[ 0], pf[ 1], pf[ 2], pf[ 3]);
        w[1] = make_float4(pf[ 4], pf[ 5], pf[ 6], pf[ 7]);
        w[2] = make_float4(pf[ 8], pf[ 9], pf[10], pf[11]);
        w[3] = make_float4(pf[12], pf[13], pf[14], Ef);
    }

    // ---- Publish + elect last block (counter needs no init) ----
    __threadfence();                  // release: ws writes to coherence point
    unsigned int old = 0;
    if (tid == 0) old = atomicAdd(cnt, 1u);
    old = __shfl(old, 0, 64);
    if ((old & (NBLK - 1u)) != NBLK - 1u) return;
    __threadfence();                  // acquire: drop stale cached ws lines

    // ---- Phase B: chain alpha through 8 block matrices ----
    float mi = fmaxf(l00, la0);
    float A0 = EXP2F(l00 - mi), A1 = EXP2F(la0 - mi);
    float A2 = 0.f, A3 = 0.f, A4 = 0.f;
    double Ed = (double)mi;
    int    Ei = 0;

    float4 mm[NBLK][4];
    #pragma unroll
    for (int k = 0; k < NBLK; ++k) {
        const float4* src = (const float4*)(ws + (size_t)k * 512 + b * 16);
        mm[k][0] = src[0]; mm[k][1] = src[1]; mm[k][2] = src[2]; mm[k][3] = src[3];
    }
    #pragma unroll
    for (int k = 0; k < NBLK; ++k) {
        float4 v0 = mm[k][0], v1 = mm[k][1], v2 = mm[k][2], v3 = mm[k][3];
        float B0 = A0 * v0.x;
        float B1 = fmaf(A0, v0.y, A1 * v1.y);
        float B2 = fmaf(A0, v0.z, fmaf(A1, v1.z, A2 * v2.y));
        float B3 = fmaf(A0, v0.w, fmaf(A1, v1.w, fmaf(A2, v2.z, A3 * v3.x)));
        float B4 = fmaf(A0, v1.x, fmaf(A1, v2.x, fmaf(A2, v2.w,
                        fmaf(A3, v3.y, A4 * v3.z))));
        Ed += (double)v3.w;
        float mx = fmaxf(fmaxf(fmaxf(B0, B1), fmaxf(B2, B3)), B4);
        int ex = (int)((__float_as_uint(mx) >> 23) & 0xffu) - 127;
        float sc = __uint_as_float((unsigned)(127 - ex) << 23);   // 2^-ex
        Ei += ex;
        A0 = B0 * sc; A1 = B1 * sc; A2 = B2 * sc; A3 = B3 * sc; A4 = B4 * sc;
    }

    float ll2 = (float)(Ed + (double)Ei) + LOG2F(A3 + A4);   // log2 likelihood
    float loss = (tid < 32) ? (-0.5f * LN2 * ll2) : 0.0f;    // -loglik_e / L
    #pragma unroll
    for (int off = 32; off > 0; off >>= 1)
        loss += __shfl_down(loss, off, 64);
    if (tid == 0) out[0] = loss * (1.0f / BB);
}

extern "C" void kernel_launch(void* const* d_in, const int* in_sizes, int n_in,
                              void* d_out, int out_size, void* d_ws, size_t ws_size,
                              hipStream_t stream) {
    const float* logit   = (const float*)d_in[0];
    const int*   targets = (const int*)d_in[2];
    float*        ws  = (float*)d_ws;
    unsigned int* cnt = (unsigned int*)((char*)d_ws + WS_CNT_OFF);
    float*        out = (float*)d_out;

    hipLaunchKernelGGL(ctc_fused, dim3(NBLK), dim3(256), 0, stream,
                       logit, targets, ws, cnt, out);
}